// Round 1
// baseline (374.232 us; speedup 1.0000x reference)
//
#include <hip/hip_runtime.h>

// ---------------------------------------------------------------------------
// BaseWindowAttention on MI355X (gfx950)
// x:[2,256,256,256]f32, w_qkv:[256,768]f32, pos_emb:[15,15]f32,
// w_out:[256,256]f32, b_out:[256]f32, rel_idx:[64,64,2]i32
// out:[2,256,256,256]f32
//
// Pipeline:
//  prep:     w_qkv^T, w_out^T -> bf16 (ws), bias[64][64] f32 (ws)
//  qkv_gemm: qkv[131072][768] bf16 (ws)  = x @ w_qkv     (MFMA 16x16x32 bf16)
//  attn:     per-window attention; ao bf16 packed into bytes [512,1024) of
//            each 1KB d_out row (no extra ws, no cross-block hazard)
//  out_gemm: out = ao @ w_out + b_out  (block covers full N=256 so it reads
//            only its own rows' ao before overwriting them)
// ---------------------------------------------------------------------------

typedef __bf16 bf16_t;
typedef __bf16 bf16x8 __attribute__((ext_vector_type(8)));
typedef float  f32x4  __attribute__((ext_vector_type(4)));

#define MFMA_BF16(a, b, c) __builtin_amdgcn_mfma_f32_16x16x32_bf16((a), (b), (c), 0, 0, 0)
#define SM_SCALE 0.17677669529663687f  // 32^-0.5

// ws layout (bytes)
#define WQKVT_OFF 0u          // bf16 [768][256]
#define WOUTT_OFF 393216u     // bf16 [256][256]
#define BIAS_OFF  524288u     // f32  [64][64]
#define QKV_OFF   540672u     // bf16 [131072][768]

__device__ __forceinline__ void gload16(const void* g, void* l) {
    // async global->LDS, 16B per lane. LDS dest = wave-uniform base + lane*16.
    __builtin_amdgcn_global_load_lds(
        (const __attribute__((address_space(1))) unsigned int*)g,
        (__attribute__((address_space(3))) unsigned int*)l,
        16, 0, 0);
}

// ---------------------------------------------------------------------------
__global__ __launch_bounds__(256) void prep_kernel(
    const float* __restrict__ w_qkv, const float* __restrict__ w_out,
    const float* __restrict__ pos_emb, const int* __restrict__ rel_idx,
    bf16_t* __restrict__ wqkvT, bf16_t* __restrict__ woutT,
    float* __restrict__ biasT)
{
    int idx = blockIdx.x * 256 + threadIdx.x;
    if (idx < 196608) {                 // wqkvT[n][k] = w_qkv[k][n]
        int n = idx >> 8, k = idx & 255;
        wqkvT[idx] = (bf16_t)w_qkv[k * 768 + n];
    } else if (idx < 262144) {          // woutT[n][k] = w_out[k][n]
        int t = idx - 196608;
        int n = t >> 8, k = t & 255;
        woutT[t] = (bf16_t)w_out[k * 256 + n];
    } else if (idx < 266240) {          // bias gather
        int t = idx - 262144;
        int i0 = rel_idx[t * 2 + 0], i1 = rel_idx[t * 2 + 1];
        biasT[t] = pos_emb[i0 * 15 + i1];
    }
}

// ---------------------------------------------------------------------------
// qkv GEMM: C[M=131072][N=768] = A[M][256](f32) * B^T[N][256](bf16), C bf16.
// 128x128 tile, 4 waves (each 64x64), BK=32, single-buffer 2-barrier loop.
// LDS chunk swizzle: slot(row,pp) holds logical chunk pl = pp ^ (row&mask).
__global__ __launch_bounds__(256) void qkv_gemm_kernel(
    const float* __restrict__ x, const bf16_t* __restrict__ wT,
    bf16_t* __restrict__ qkv)
{
    __shared__ __align__(16) float  As[128 * 32];   // 16KB f32
    __shared__ __align__(16) bf16_t Bs[128 * 32];   // 8KB bf16

    const int tid = threadIdx.x;
    const int b = blockIdx.x;
    const int bm = b & 1023, bn = b >> 10;          // bm-major for x locality
    const int m0 = bm << 7, n0 = bn << 7;
    const int lane = tid & 63, wv = tid >> 6;
    const int g = lane >> 4, c = lane & 15;
    const int wm = wv >> 1, wn = wv & 1;

    f32x4 acc[4][4];
    f32x4 z4 = {0.f, 0.f, 0.f, 0.f};
#pragma unroll
    for (int i = 0; i < 4; ++i)
#pragma unroll
        for (int j = 0; j < 4; ++j) acc[i][j] = z4;

    const f32x4* Asf = (const f32x4*)As;
    const f32x4* Bsf = (const f32x4*)Bs;

    for (int ks = 0; ks < 8; ++ks) {
        const int k0 = ks << 5;
        // stage A: 1024 x 16B chunks (f32), swizzle key row&7
#pragma unroll
        for (int i = 0; i < 4; ++i) {
            int q = i * 256 + tid;
            int row = q >> 3;
            int pl = (q & 7) ^ (row & 7);
            gload16(x + (m0 + row) * 256 + k0 + pl * 4,
                    (char*)As + (i * 256 + wv * 64) * 16);
        }
        // stage B: 512 x 16B chunks (bf16), swizzle key row&3
#pragma unroll
        for (int i = 0; i < 2; ++i) {
            int q = i * 256 + tid;
            int row = q >> 2;
            int pl = (q & 3) ^ (row & 3);
            gload16(wT + (n0 + row) * 256 + k0 + pl * 8,
                    (char*)Bs + (i * 256 + wv * 64) * 16);
        }
        __syncthreads();   // compiler emits vmcnt(0) drain before barrier

        bf16x8 af[4], bfr[4];
#pragma unroll
        for (int mi = 0; mi < 4; ++mi) {
            int r = wm * 64 + mi * 16 + c;
            f32x4 a0 = Asf[r * 8 + ((2 * g)     ^ (r & 7))];
            f32x4 a1 = Asf[r * 8 + ((2 * g + 1) ^ (r & 7))];
            bf16x8 t;
            t[0] = (bf16_t)a0[0]; t[1] = (bf16_t)a0[1];
            t[2] = (bf16_t)a0[2]; t[3] = (bf16_t)a0[3];
            t[4] = (bf16_t)a1[0]; t[5] = (bf16_t)a1[1];
            t[6] = (bf16_t)a1[2]; t[7] = (bf16_t)a1[3];
            af[mi] = t;
        }
#pragma unroll
        for (int ni = 0; ni < 4; ++ni) {
            int r = wn * 64 + ni * 16 + c;
            f32x4 t = Bsf[r * 4 + (g ^ (r & 3))];
            bfr[ni] = __builtin_bit_cast(bf16x8, t);
        }
#pragma unroll
        for (int mi = 0; mi < 4; ++mi)
#pragma unroll
            for (int ni = 0; ni < 4; ++ni)
                acc[mi][ni] = MFMA_BF16(af[mi], bfr[ni], acc[mi][ni]);
        __syncthreads();
    }

    // epilogue: D layout col=lane&15, row=4*(lane>>4)+reg (verified m89/m91)
#pragma unroll
    for (int mi = 0; mi < 4; ++mi)
#pragma unroll
        for (int ni = 0; ni < 4; ++ni)
#pragma unroll
            for (int rg = 0; rg < 4; ++rg) {
                int grow = m0 + wm * 64 + mi * 16 + 4 * g + rg;
                int gcol = n0 + wn * 64 + ni * 16 + c;
                qkv[(size_t)grow * 768 + gcol] = (bf16_t)acc[mi][ni][rg];
            }
}

// ---------------------------------------------------------------------------
// Window attention. Block = one (l, window), 4 waves, 2 heads/wave.
// Per head: S = Q K^T (16 MFMA), softmax in-register (16-lane shfl reduce),
// P and V^T staged in per-wave XOR-swizzled LDS, O = P V (16 MFMA).
// ao (bf16) written into bytes [512,1024) of each output row.
__global__ __launch_bounds__(256) void attn_kernel(
    const bf16_t* __restrict__ qkv, const float* __restrict__ biasT,
    float* __restrict__ aout)
{
    __shared__ __align__(16) bf16_t P_s[4][64 * 64];   // 8KB/wave
    __shared__ __align__(16) bf16_t Vt_s[4][32 * 64];  // 4KB/wave

    const int tid = threadIdx.x;
    const int lane = tid & 63, wv = tid >> 6;
    const int g = lane >> 4, c = lane & 15;
    const int b = blockIdx.x;
    const int l = b >> 10, win = b & 1023;
    const int whi = win >> 5, wwi = win & 31;
    const int rbase = l * 65536 + whi * 2048 + wwi * 8;  // token row base

    bf16_t* Pw = P_s[wv];
    bf16_t* Vw = Vt_s[wv];

    for (int hh = 0; hh < 2; ++hh) {
        const int h = wv * 2 + hh;

        // Q (A-frag) / K (B-frag) straight from global, 16B per lane.
        bf16x8 qf[4], kf[4];
#pragma unroll
        for (int mi = 0; mi < 4; ++mi) {
            int t = mi * 16 + c;
            size_t r = (size_t)(rbase + (t >> 3) * 256 + (t & 7));
            qf[mi] = *(const bf16x8*)(qkv + r * 768 + h * 32 + g * 8);
            kf[mi] = *(const bf16x8*)(qkv + r * 768 + 256 + h * 32 + g * 8);
        }
        f32x4 s[4][4];
        f32x4 z4 = {0.f, 0.f, 0.f, 0.f};
#pragma unroll
        for (int i = 0; i < 4; ++i)
#pragma unroll
            for (int j = 0; j < 4; ++j) s[i][j] = z4;
#pragma unroll
        for (int mi = 0; mi < 4; ++mi)
#pragma unroll
            for (int ni = 0; ni < 4; ++ni)
                s[mi][ni] = MFMA_BF16(qf[mi], kf[ni], s[mi][ni]);

        // V -> Vt LDS (transposed, swizzled): Vt[dh][tok]
        {
            int t = lane;
            size_t r = (size_t)(rbase + (t >> 3) * 256 + (t & 7));
#pragma unroll
            for (int d0 = 0; d0 < 4; ++d0) {
                bf16x8 v = *(const bf16x8*)(qkv + r * 768 + 512 + h * 32 + d0 * 8);
#pragma unroll
                for (int j = 0; j < 8; ++j) {
                    int dh = d0 * 8 + j;
                    Vw[dh * 64 + ((((t >> 3) ^ (dh & 7)) << 3) | (t & 7))] = v[j];
                }
            }
        }

        // softmax: rows = 16mi+4g+rg, cols = 16ni+c. Reduce over 16 c-lanes.
        float rs[4][4];
#pragma unroll
        for (int mi = 0; mi < 4; ++mi) {
#pragma unroll
            for (int rg = 0; rg < 4; ++rg) {
                int row = mi * 16 + 4 * g + rg;
                float v0 = s[mi][0][rg] * SM_SCALE + biasT[row * 64 + c];
                float v1 = s[mi][1][rg] * SM_SCALE + biasT[row * 64 + 16 + c];
                float v2 = s[mi][2][rg] * SM_SCALE + biasT[row * 64 + 32 + c];
                float v3 = s[mi][3][rg] * SM_SCALE + biasT[row * 64 + 48 + c];
                float mx = fmaxf(fmaxf(v0, v1), fmaxf(v2, v3));
                mx = fmaxf(mx, __shfl_xor(mx, 1));
                mx = fmaxf(mx, __shfl_xor(mx, 2));
                mx = fmaxf(mx, __shfl_xor(mx, 4));
                mx = fmaxf(mx, __shfl_xor(mx, 8));
                float p0 = __expf(v0 - mx);
                float p1 = __expf(v1 - mx);
                float p2 = __expf(v2 - mx);
                float p3 = __expf(v3 - mx);
                float sm = p0 + p1 + p2 + p3;
                sm += __shfl_xor(sm, 1);
                sm += __shfl_xor(sm, 2);
                sm += __shfl_xor(sm, 4);
                sm += __shfl_xor(sm, 8);
                rs[mi][rg] = 1.0f / sm;
                int rk = row & 7, sub = c & 7, hi = c >> 3;
                Pw[row * 64 + (((0 + hi) ^ rk) << 3) + sub] = (bf16_t)p0;
                Pw[row * 64 + (((2 + hi) ^ rk) << 3) + sub] = (bf16_t)p1;
                Pw[row * 64 + (((4 + hi) ^ rk) << 3) + sub] = (bf16_t)p2;
                Pw[row * 64 + (((6 + hi) ^ rk) << 3) + sub] = (bf16_t)p3;
            }
        }

        // O = P V  (K = 64 tokens -> 2 K-steps)
        f32x4 o[4][2];
#pragma unroll
        for (int i = 0; i < 4; ++i) { o[i][0] = z4; o[i][1] = z4; }
#pragma unroll
        for (int ks = 0; ks < 2; ++ks) {
            bf16x8 pa[4], vb[2];
#pragma unroll
            for (int mi = 0; mi < 4; ++mi) {
                int r = mi * 16 + c;
                pa[mi] = *(const bf16x8*)(Pw + r * 64 + (((4 * ks + g) ^ (r & 7)) << 3));
            }
#pragma unroll
            for (int ni = 0; ni < 2; ++ni) {
                int r = ni * 16 + c;
                vb[ni] = *(const bf16x8*)(Vw + r * 64 + (((4 * ks + g) ^ (r & 7)) << 3));
            }
#pragma unroll
            for (int mi = 0; mi < 4; ++mi)
#pragma unroll
                for (int ni = 0; ni < 2; ++ni)
                    o[mi][ni] = MFMA_BF16(pa[mi], vb[ni], o[mi][ni]);
        }

        // store ao (bf16) into second half of each 1KB out row
#pragma unroll
        for (int mi = 0; mi < 4; ++mi)
#pragma unroll
            for (int ni = 0; ni < 2; ++ni)
#pragma unroll
                for (int rg = 0; rg < 4; ++rg) {
                    int t = mi * 16 + 4 * g + rg;
                    size_t r = (size_t)(rbase + (t >> 3) * 256 + (t & 7));
                    bf16_t* ao = (bf16_t*)((char*)aout + r * 1024 + 512);
                    ao[h * 32 + ni * 16 + c] = (bf16_t)(o[mi][ni][rg] * rs[mi][rg]);
                }
    }
}

// ---------------------------------------------------------------------------
// out GEMM: out[M][256] = ao[M][256](bf16, packed in out rows) @ w_out + b.
// Block = 128 rows x full N=256 (8 waves of 64x64) so each block reads only
// its own rows' ao (all reads precede epilogue writes -> no hazard).
__global__ __launch_bounds__(512) void out_gemm_kernel(
    const bf16_t* __restrict__ wT, const float* __restrict__ b_out,
    float* out)
{
    __shared__ __align__(16) bf16_t As[128 * 32];   // 8KB
    __shared__ __align__(16) bf16_t Bs[256 * 32];   // 16KB

    const int tid = threadIdx.x;
    const int lane = tid & 63, wv = tid >> 6;
    const int g = lane >> 4, c = lane & 15;
    const int wm = wv >> 2, wn = wv & 3;
    const int m0 = blockIdx.x << 7;

    f32x4 acc[4][4];
    f32x4 z4 = {0.f, 0.f, 0.f, 0.f};
#pragma unroll
    for (int i = 0; i < 4; ++i)
#pragma unroll
        for (int j = 0; j < 4; ++j) acc[i][j] = z4;

    const f32x4* Asf = (const f32x4*)As;
    const f32x4* Bsf = (const f32x4*)Bs;

    for (int ks = 0; ks < 8; ++ks) {
        {   // stage A: 512 chunks, 1/thread
            int q = tid;
            int row = q >> 2;
            int pl = (q & 3) ^ (row & 3);
            gload16((const char*)out + (size_t)(m0 + row) * 1024 + 512 + ks * 64 + pl * 16,
                    (char*)As + wv * 1024);
        }
#pragma unroll
        for (int i = 0; i < 2; ++i) {   // stage B: 1024 chunks, 2/thread
            int q = i * 512 + tid;
            int row = q >> 2;
            int pl = (q & 3) ^ (row & 3);
            gload16(wT + row * 256 + ks * 32 + pl * 8,
                    (char*)Bs + (i * 512 + wv * 64) * 16);
        }
        __syncthreads();

        bf16x8 af[4], bfr[4];
#pragma unroll
        for (int mi = 0; mi < 4; ++mi) {
            int r = wm * 64 + mi * 16 + c;
            f32x4 t = Asf[r * 4 + (g ^ (r & 3))];
            af[mi] = __builtin_bit_cast(bf16x8, t);
        }
#pragma unroll
        for (int ni = 0; ni < 4; ++ni) {
            int r = wn * 64 + ni * 16 + c;
            f32x4 t = Bsf[r * 4 + (g ^ (r & 3))];
            bfr[ni] = __builtin_bit_cast(bf16x8, t);
        }
#pragma unroll
        for (int mi = 0; mi < 4; ++mi)
#pragma unroll
            for (int ni = 0; ni < 4; ++ni)
                acc[mi][ni] = MFMA_BF16(af[mi], bfr[ni], acc[mi][ni]);
        __syncthreads();
    }

#pragma unroll
    for (int ni = 0; ni < 4; ++ni) {
        int gcol = wn * 64 + ni * 16 + c;
        float bo = b_out[gcol];
#pragma unroll
        for (int mi = 0; mi < 4; ++mi)
#pragma unroll
            for (int rg = 0; rg < 4; ++rg) {
                int grow = m0 + wm * 64 + mi * 16 + 4 * g + rg;
                out[(size_t)grow * 256 + gcol] = acc[mi][ni][rg] + bo;
            }
    }
}

// ---------------------------------------------------------------------------
extern "C" void kernel_launch(void* const* d_in, const int* in_sizes, int n_in,
                              void* d_out, int out_size, void* d_ws, size_t ws_size,
                              hipStream_t stream) {
    const float* x       = (const float*)d_in[0];
    const float* w_qkv   = (const float*)d_in[1];
    const float* pos_emb = (const float*)d_in[2];
    const float* w_out   = (const float*)d_in[3];
    const float* b_out   = (const float*)d_in[4];
    const int*   rel_idx = (const int*)d_in[5];

    char* ws = (char*)d_ws;
    bf16_t* wqkvT = (bf16_t*)(ws + WQKVT_OFF);
    bf16_t* woutT = (bf16_t*)(ws + WOUTT_OFF);
    float*  biasT = (float*)(ws + BIAS_OFF);
    bf16_t* qkv   = (bf16_t*)(ws + QKV_OFF);   // needs ~192.5MB of ws
    float*  out   = (float*)d_out;

    prep_kernel<<<1040, 256, 0, stream>>>(w_qkv, w_out, pos_emb, rel_idx,
                                          wqkvT, woutT, biasT);
    qkv_gemm_kernel<<<6144, 256, 0, stream>>>(x, wqkvT, qkv);
    attn_kernel<<<2048, 256, 0, stream>>>(qkv, biasT, out);
    out_gemm_kernel<<<1024, 512, 0, stream>>>(woutT, b_out, out);
}